// Round 1
// baseline (266.898 us; speedup 1.0000x reference)
//
#include <hip/hip_runtime.h>
#include <hip/hip_bf16.h>

// ---------------------------------------------------------------------------
// CVXPolicy_DoubleIntegrator, R3: occupancy 2x — 1024-thread blocks, 16 waves,
// 16 rows/wave. Same LDS footprint (weights 96KB + hbuf 58KB + cb 1.8KB), so
// still 1 block/CU, but 4 waves/SIMD instead of 2. Biases moved to LDS to keep
// VGPR <= 128 (required for 16-wave blocks).
//
// Packed weights (bf16, scatter folded into W3, t-row of W1 removed):
//   PW1: frag (kt*7+nt), kt<6, nt<7        -> shorts [0, 21504)
//   PW2: frag 42+kt*7+nt, kt<4, nt<7       -> shorts [21504, 35840)
//   PW3: frag 70+kt*6+nt, kt<4, nt<6       -> shorts [35840, 48128)
//   floats at short-index 48128: w0[112], b1[112], b2[112], bq[96]
// frag = 512 shorts: element e = lane*8+j -> B[k = kt*32+(lane>>4)*8+j][n = nt*16+(lane&15)]
//
// MFMA 16x16x32 bf16 layouts (verified in R1, passed):
//   A:   lane -> A[m = lane&15][k = (lane>>4)*8 + j]
//   C/D: lane -> col = lane&15, row = (lane>>4)*4 + reg
// ---------------------------------------------------------------------------

typedef __attribute__((ext_vector_type(8))) short short8;
typedef __attribute__((ext_vector_type(4))) short short4v;
typedef __attribute__((ext_vector_type(4))) float f32x4;

#define HST 116  // hbuf row stride in shorts (232B: 8B-aligned, uniform banks)

__device__ __forceinline__ unsigned short f2bf(float f) {
  unsigned u = __float_as_uint(f);
  u += 0x7fffu + ((u >> 16) & 1u);  // RNE (finite values only)
  return (unsigned short)(u >> 16);
}
__device__ __forceinline__ float tanh_fast(float x) {
  float ax = fabsf(x);
  float e = __builtin_amdgcn_exp2f(ax * -2.88539008177792681f);  // exp(-2ax)
  float r = (1.f - e) * __builtin_amdgcn_rcpf(1.f + e);
  return copysignf(r, x);
}

// ---------------------------------------------------------------------------
// Prep: pack weights bf16, fold scatter into W3, drop t-row (kept as w0 f32).
// ---------------------------------------------------------------------------
__global__ void cvx_prep(const float* __restrict__ W1, const float* __restrict__ b1,
                         const float* __restrict__ W2, const float* __restrict__ b2,
                         const float* __restrict__ W3, const float* __restrict__ b3,
                         short* __restrict__ pw) {
  int idx = blockIdx.x * 256 + threadIdx.x;

  if (idx < 21504) {                        // PW1: 6 kt * 7 nt * 512
    int kt = idx / 3584, rem = idx % 3584;
    int nt = rem / 512, e = rem % 512;
    int lane = e >> 3, j = e & 7;
    int k = kt * 32 + (lane >> 4) * 8 + j;  // z index; W1 row k+1
    int n = nt * 16 + (lane & 15);
    float wv = (n < 100) ? W1[(k + 1) * 100 + n] : 0.f;
    pw[(kt * 7 + nt) * 512 + e] = (short)f2bf(wv);
    return;
  }
  idx -= 21504;
  if (idx < 14336) {                        // PW2: 4 kt * 7 nt * 512
    int kt = idx / 3584, rem = idx % 3584;
    int nt = rem / 512, e = rem % 512;
    int lane = e >> 3, j = e & 7;
    int k = kt * 32 + (lane >> 4) * 8 + j;
    int n = nt * 16 + (lane & 15);
    float wv = (k < 100 && n < 100) ? W2[k * 100 + n] : 0.f;
    pw[21504 + (kt * 7 + nt) * 512 + e] = (short)f2bf(wv);
    return;
  }
  idx -= 14336;
  if (idx < 12288) {                        // PW3 folded: 4 kt * 6 nt * 512
    int kt = idx / 3072, rem = idx % 3072;
    int nt = rem / 512, e = rem % 512;
    int lane = e >> 3, j = e & 7;
    int k = kt * 32 + (lane >> 4) * 8 + j;
    int u = nt * 16 + (lane & 15);          // u < 96
    float wv = 0.f;
    if (k < 100) {
      const float* wr = W3 + k * 192;
      if (u <= 31) wv += wr[3 * u + 3];                     // u = i
      if ((u & 1) == 0 && u <= 62) wv += wr[2 * u + 4];     // u = 2i
      if (u % 3 == 0 && u <= 93) wv += wr[(5 * u) / 3 + 5]; // u = 3i
    }
    pw[35840 + (kt * 6 + nt) * 512 + e] = (short)f2bf(wv);
    return;
  }
  idx -= 12288;
  float* cb = (float*)(pw + 48128);
  if (idx < 112) { cb[idx] = (idx < 100) ? W1[idx] : 0.f; return; }        // w0 = W1 row 0
  idx -= 112;
  if (idx < 112) { cb[112 + idx] = (idx < 100) ? b1[idx] : 0.f; return; }
  idx -= 112;
  if (idx < 112) { cb[224 + idx] = (idx < 100) ? b2[idx] : 0.f; return; }
  idx -= 112;
  if (idx < 96) {
    int u = idx;
    float v = 0.f;
    if (u <= 31) v += b3[3 * u + 3];
    if ((u & 1) == 0 && u <= 62) v += b3[2 * u + 4];
    if (u % 3 == 0 && u <= 93) v += b3[(5 * u) / 3 + 5];
    cb[336 + u] = v;
  }
}

// ---------------------------------------------------------------------------
// Main fused kernel: 1024 thr (16 waves), 1 block/CU (grid 256),
// 2 tiles x 256 rows, 16 rows per wave per tile.
// ---------------------------------------------------------------------------
__global__ __launch_bounds__(1024, 4) void cvx_main(
    const float* __restrict__ zin, const float* __restrict__ tin,
    const short* __restrict__ pw, float* __restrict__ out) {
  __shared__ __align__(16) short wbuf[48128];        // 96,256 B: all weights
  __shared__ __align__(16) short hbuf[16 * 16 * HST]; // 59,392 B: per-wave h (16 rows)
  __shared__ __align__(16) float cbl[448];           // 1,792 B: w0|b1|b2|bq

  const int tid = threadIdx.x;
  const int wid = tid >> 6;
  const int lane = tid & 63;
  const int l15 = lane & 15;
  const int qd = lane >> 4;

  // stage ALL weights into LDS (once per block)
  for (int f = wid; f < 94; f += 16) {
    const short* g = pw + f * 512 + lane * 8;
    __builtin_amdgcn_global_load_lds(
        (const __attribute__((address_space(1))) void*)g,
        (__attribute__((address_space(3))) void*)&wbuf[f * 512], 16, 0, 0);
  }
  // stage bias/w0 block into LDS (f32)
  if (tid < 448) cbl[tid] = ((const float*)(pw + 48128))[tid];

  const int row0 = blockIdx.x * 512 + wid * 16;
  const int hb = wid * 16 * HST;

  // prefetch tile 0 z,t into registers (overlaps weight staging)
  f32x4 zc[6][2];
  float tc;
  {
    const float* zr = zin + (size_t)(row0 + l15) * 192 + qd * 8;
#pragma unroll
    for (int kt = 0; kt < 6; kt++) {
      zc[kt][0] = *(const f32x4*)(zr + kt * 32);
      zc[kt][1] = *(const f32x4*)(zr + kt * 32 + 4);
    }
    tc = tin[row0 + l15];
  }

  __syncthreads();  // the only barrier: weights + cb resident from here on

  auto ldh = [&](int off) -> short8 {   // 8B-aligned LDS read of 8 shorts
    short4v a = *(const short4v*)&hbuf[off];
    short4v b = *(const short4v*)&hbuf[off + 4];
    return __builtin_shufflevector(a, b, 0, 1, 2, 3, 4, 5, 6, 7);
  };

#pragma unroll 1
  for (int it = 0; it < 2; ++it) {
    const int rb = row0 + it * 256;

    // ---- build A fragments from prefetched z ----
    short8 XA[6];
#pragma unroll
    for (int kt = 0; kt < 6; kt++) {
      union { short8 s; __hip_bfloat162 h[4]; } u;
      f32x4 a = zc[kt][0], b = zc[kt][1];
      u.h[0] = __float22bfloat162_rn(make_float2(a[0], a[1]));
      u.h[1] = __float22bfloat162_rn(make_float2(a[2], a[3]));
      u.h[2] = __float22bfloat162_rn(make_float2(b[0], b[1]));
      u.h[3] = __float22bfloat162_rn(make_float2(b[2], b[3]));
      XA[kt] = u.s;
    }
    float tv = tc;

    // ---- prefetch next tile while this one computes ----
    if (it == 0) {
      const float* zr = zin + (size_t)(row0 + 256 + l15) * 192 + qd * 8;
#pragma unroll
      for (int kt = 0; kt < 6; kt++) {
        zc[kt][0] = *(const f32x4*)(zr + kt * 32);
        zc[kt][1] = *(const f32x4*)(zr + kt * 32 + 4);
      }
      tc = tin[row0 + 256 + l15];
    }

    // ---- Layer 1: [16,192] x [192,112] ----
    f32x4 acc[7];
#pragma unroll
    for (int nt = 0; nt < 7; nt++) {
      f32x4 zzz = {0.f, 0.f, 0.f, 0.f};
      acc[nt] = zzz;
    }
#pragma unroll
    for (int kt = 0; kt < 6; kt++)
#pragma unroll
      for (int nt = 0; nt < 7; nt++) {
        short8 bf = *(const short8*)&wbuf[(kt * 7 + nt) * 512 + lane * 8];
        acc[nt] = __builtin_amdgcn_mfma_f32_16x16x32_bf16(XA[kt], bf, acc[nt], 0, 0, 0);
      }
    // t rank-1 fixup + bias + tanh -> hbuf
    float tr[4];
#pragma unroll
    for (int r = 0; r < 4; r++) tr[r] = __shfl(tv, qd * 4 + r);
#pragma unroll
    for (int nt = 0; nt < 7; nt++) {
      float w0v = cbl[nt * 16 + l15];
      float b1v = cbl[112 + nt * 16 + l15];
#pragma unroll
      for (int r = 0; r < 4; r++) {
        float v = fmaf(tr[r], w0v, acc[nt][r] + b1v);
        hbuf[hb + (qd * 4 + r) * HST + nt * 16 + l15] = (short)f2bf(tanh_fast(v));
      }
    }

    // ---- Layer 2: [16,128] x [128,112] (kt=3: K rows 112..127 are B-zero) ----
    short8 HA[4];
    {
      int ro = hb + l15 * HST;
#pragma unroll
      for (int kt = 0; kt < 3; kt++) HA[kt] = ldh(ro + kt * 32 + qd * 8);
      HA[3] = ldh(ro + 96 + (qd & 1) * 8);  // qd>=2 garbage x B-zero = 0
    }
#pragma unroll
    for (int nt = 0; nt < 7; nt++) {
      f32x4 zzz = {0.f, 0.f, 0.f, 0.f};
      acc[nt] = zzz;
    }
#pragma unroll
    for (int kt = 0; kt < 4; kt++)
#pragma unroll
      for (int nt = 0; nt < 7; nt++) {
        short8 bf = *(const short8*)&wbuf[(42 + kt * 7 + nt) * 512 + lane * 8];
        acc[nt] = __builtin_amdgcn_mfma_f32_16x16x32_bf16(HA[kt], bf, acc[nt], 0, 0, 0);
      }
#pragma unroll
    for (int nt = 0; nt < 7; nt++) {
      float b2v = cbl[224 + nt * 16 + l15];
#pragma unroll
      for (int r = 0; r < 4; r++) {
        float v = acc[nt][r] + b2v;
        hbuf[hb + (qd * 4 + r) * HST + nt * 16 + l15] = (short)f2bf(tanh_fast(v));
      }
    }

    // ---- Layer 3 (scatter-folded): [16,128] x [128,96] -> q ----
    {
      int ro = hb + l15 * HST;
#pragma unroll
      for (int kt = 0; kt < 3; kt++) HA[kt] = ldh(ro + kt * 32 + qd * 8);
      HA[3] = ldh(ro + 96 + (qd & 1) * 8);
    }
    f32x4 qa[6];
#pragma unroll
    for (int nt = 0; nt < 6; nt++) {
      f32x4 zzz = {0.f, 0.f, 0.f, 0.f};
      qa[nt] = zzz;
    }
#pragma unroll
    for (int kt = 0; kt < 4; kt++)
#pragma unroll
      for (int nt = 0; nt < 6; nt++) {
        short8 bf = *(const short8*)&wbuf[(70 + kt * 6 + nt) * 512 + lane * 8];
        qa[nt] = __builtin_amdgcn_mfma_f32_16x16x32_bf16(HA[kt], bf, qa[nt], 0, 0, 0);
      }

    // ---- QP epilogue ----
#pragma unroll
    for (int nt = 0; nt < 6; nt++) {
      float bq = cbl[336 + nt * 16 + l15];
      qa[nt][0] += bq; qa[nt][1] += bq;
      qa[nt][2] += bq; qa[nt][3] += bq;
    }
    f32x4 rs = {0.f, 0.f, 0.f, 0.f};
#pragma unroll
    for (int nt = 0; nt < 6; nt++) rs += qa[nt] * qa[nt];
    float rv[4];
#pragma unroll
    for (int r = 0; r < 4; r++) {
      float v = rs[r];
      v += __shfl_xor(v, 1);
      v += __shfl_xor(v, 2);
      v += __shfl_xor(v, 4);
      v += __shfl_xor(v, 8);
      rv[r] = v;
    }
    float r2 = rv[l15 & 3];
    float s = __builtin_amdgcn_exp2f(__builtin_amdgcn_logf(r2) * 0.333333333333f);
#pragma unroll
    for (int itn = 0; itn < 8; itn++) {
      float one = 1.f + s;
      float fv = fmaf(s * one, one, -r2);
      float fp = one * fmaf(2.f, s, one);
      s = fmaxf(s - fv * __builtin_amdgcn_rcpf(fp), 0.f);
    }
    float myinv = -__builtin_amdgcn_rcpf(1.f + s);
#pragma unroll
    for (int r = 0; r < 4; r++) {
      float inv = __shfl(myinv, (lane & 48) | r);
      float* orow = out + (size_t)(rb + qd * 4 + r) * 96;
#pragma unroll
      for (int nt = 0; nt < 6; nt++)
        orow[nt * 16 + l15] = qa[nt][r] * inv;
    }
  }
}

extern "C" void kernel_launch(void* const* d_in, const int* in_sizes, int n_in,
                              void* d_out, int out_size, void* d_ws, size_t ws_size,
                              hipStream_t stream) {
  const float* z  = (const float*)d_in[0];
  const float* t  = (const float*)d_in[1];
  const float* W1 = (const float*)d_in[2];
  const float* b1 = (const float*)d_in[3];
  const float* W2 = (const float*)d_in[4];
  const float* b2 = (const float*)d_in[5];
  const float* W3 = (const float*)d_in[6];
  const float* b3 = (const float*)d_in[7];
  float* out = (float*)d_out;
  int B = in_sizes[0] / 192;                 // 131072

  short* pw = (short*)d_ws;                  // 97,984 bytes used
  cvx_prep<<<190, 256, 0, stream>>>(W1, b1, W2, b2, W3, b3, pw);
  cvx_main<<<B / 512, 1024, 0, stream>>>(z, t, pw, out);
}

// Round 2
// 199.159 us; speedup vs baseline: 1.3401x; 1.3401x over previous
//
#include <hip/hip_runtime.h>
#include <hip/hip_bf16.h>

// ---------------------------------------------------------------------------
// CVXPolicy_DoubleIntegrator, R4: weights-from-L2, hbuf-only LDS, 2 blocks/CU.
//
// R3 post-mortem: 1024-thr blocks got VGPR-capped to 64 -> scratch spill
// (FETCH/WRITE 4.4x, dur 2.2x worse). R4 buys the same 4 waves/SIMD by
// SHRINKING LDS instead: weights (96KB) are read as B-fragments directly from
// global (L2-broadcast, ~385MB total over 34.5TB/s L2 = ~11us), LDS holds only
// the wave-private h round-trip buffer (59KB) -> 2 blocks/CU co-resident.
// Zero barriers: waves fully independent.
//
// Packed weights (bf16, scatter folded into W3, t-row of W1 removed):
//   PW1: frag (kt*7+nt), kt<6, nt<7        -> shorts [0, 21504)
//   PW2: frag 42+kt*7+nt, kt<4, nt<7       -> shorts [21504, 35840)
//   PW3: frag 70+kt*6+nt, kt<4, nt<6       -> shorts [35840, 48128)
//   floats at short-index 48128: w0[112], b1[112], b2[112], bq[96]
// frag = 512 shorts: element e = lane*8+j -> B[k = kt*32+(lane>>4)*8+j][n = nt*16+(lane&15)]
//
// MFMA 16x16x32 bf16 layouts (verified in R1, passed):
//   A:   lane -> A[m = lane&15][k = (lane>>4)*8 + j]
//   C/D: lane -> col = lane&15, row = (lane>>4)*4 + reg
// ---------------------------------------------------------------------------

typedef __attribute__((ext_vector_type(8))) short short8;
typedef __attribute__((ext_vector_type(4))) short short4v;
typedef __attribute__((ext_vector_type(4))) float f32x4;

#define HST 116  // hbuf row stride in shorts (232B: 8B-aligned, uniform banks)

__device__ __forceinline__ unsigned short f2bf(float f) {
  unsigned u = __float_as_uint(f);
  u += 0x7fffu + ((u >> 16) & 1u);  // RNE (finite values only)
  return (unsigned short)(u >> 16);
}
__device__ __forceinline__ float tanh_fast(float x) {
  float ax = fabsf(x);
  float e = __builtin_amdgcn_exp2f(ax * -2.88539008177792681f);  // exp(-2ax)
  float r = (1.f - e) * __builtin_amdgcn_rcpf(1.f + e);
  return copysignf(r, x);
}

// ---------------------------------------------------------------------------
// Prep: pack weights bf16, fold scatter into W3, drop t-row (kept as w0 f32).
// ---------------------------------------------------------------------------
__global__ void cvx_prep(const float* __restrict__ W1, const float* __restrict__ b1,
                         const float* __restrict__ W2, const float* __restrict__ b2,
                         const float* __restrict__ W3, const float* __restrict__ b3,
                         short* __restrict__ pw) {
  int idx = blockIdx.x * 256 + threadIdx.x;

  if (idx < 21504) {                        // PW1: 6 kt * 7 nt * 512
    int kt = idx / 3584, rem = idx % 3584;
    int nt = rem / 512, e = rem % 512;
    int lane = e >> 3, j = e & 7;
    int k = kt * 32 + (lane >> 4) * 8 + j;  // z index; W1 row k+1
    int n = nt * 16 + (lane & 15);
    float wv = (n < 100) ? W1[(k + 1) * 100 + n] : 0.f;
    pw[(kt * 7 + nt) * 512 + e] = (short)f2bf(wv);
    return;
  }
  idx -= 21504;
  if (idx < 14336) {                        // PW2: 4 kt * 7 nt * 512
    int kt = idx / 3584, rem = idx % 3584;
    int nt = rem / 512, e = rem % 512;
    int lane = e >> 3, j = e & 7;
    int k = kt * 32 + (lane >> 4) * 8 + j;
    int n = nt * 16 + (lane & 15);
    float wv = (k < 100 && n < 100) ? W2[k * 100 + n] : 0.f;
    pw[21504 + (kt * 7 + nt) * 512 + e] = (short)f2bf(wv);
    return;
  }
  idx -= 14336;
  if (idx < 12288) {                        // PW3 folded: 4 kt * 6 nt * 512
    int kt = idx / 3072, rem = idx % 3072;
    int nt = rem / 512, e = rem % 512;
    int lane = e >> 3, j = e & 7;
    int k = kt * 32 + (lane >> 4) * 8 + j;
    int u = nt * 16 + (lane & 15);          // u < 96
    float wv = 0.f;
    if (k < 100) {
      const float* wr = W3 + k * 192;
      if (u <= 31) wv += wr[3 * u + 3];                     // u = i
      if ((u & 1) == 0 && u <= 62) wv += wr[2 * u + 4];     // u = 2i
      if (u % 3 == 0 && u <= 93) wv += wr[(5 * u) / 3 + 5]; // u = 3i
    }
    pw[35840 + (kt * 6 + nt) * 512 + e] = (short)f2bf(wv);
    return;
  }
  idx -= 12288;
  float* cb = (float*)(pw + 48128);
  if (idx < 112) { cb[idx] = (idx < 100) ? W1[idx] : 0.f; return; }        // w0 = W1 row 0
  idx -= 112;
  if (idx < 112) { cb[112 + idx] = (idx < 100) ? b1[idx] : 0.f; return; }
  idx -= 112;
  if (idx < 112) { cb[224 + idx] = (idx < 100) ? b2[idx] : 0.f; return; }
  idx -= 112;
  if (idx < 96) {
    int u = idx;
    float v = 0.f;
    if (u <= 31) v += b3[3 * u + 3];
    if ((u & 1) == 0 && u <= 62) v += b3[2 * u + 4];
    if (u % 3 == 0 && u <= 93) v += b3[(5 * u) / 3 + 5];
    cb[336 + u] = v;
  }
}

// ---------------------------------------------------------------------------
// Main fused kernel: 512 thr (8 waves), 256 rows/block (32 rows/wave),
// grid 512 = 2 blocks/CU. No barriers, no weight staging.
// ---------------------------------------------------------------------------
__global__ __launch_bounds__(512, 4) void cvx_main(
    const float* __restrict__ zin, const float* __restrict__ tin,
    const short* __restrict__ pw, float* __restrict__ out) {
  __shared__ __align__(16) short hbuf[8 * 32 * HST];  // 59,392 B: per-wave h

  const int tid = threadIdx.x;
  const int wid = tid >> 6;
  const int lane = tid & 63;
  const int l15 = lane & 15;
  const int qd = lane >> 4;

  // biases / w0 into registers (wave-uniform-per-l15, L2/L3-cached)
  const float* cb = (const float*)(pw + 48128);
  float w0v[7], b1v[7], b2v[7], bqv[6];
#pragma unroll
  for (int nt = 0; nt < 7; nt++) {
    w0v[nt] = cb[nt * 16 + l15];
    b1v[nt] = cb[112 + nt * 16 + l15];
    b2v[nt] = cb[224 + nt * 16 + l15];
  }
#pragma unroll
  for (int nt = 0; nt < 6; nt++) bqv[nt] = cb[336 + nt * 16 + l15];

  const int row0 = blockIdx.x * 256 + wid * 32;
  const int hb = wid * 32 * HST;
  const short* wfrag = pw + lane * 8;  // per-lane base for all B fragments

  // ---- load this wave's 32 rows of z,t ----
  f32x4 zc[2][6][2];
  float tc[2];
#pragma unroll
  for (int mt = 0; mt < 2; mt++) {
    const float* zr = zin + (size_t)(row0 + mt * 16 + l15) * 192 + qd * 8;
#pragma unroll
    for (int kt = 0; kt < 6; kt++) {
      zc[mt][kt][0] = *(const f32x4*)(zr + kt * 32);
      zc[mt][kt][1] = *(const f32x4*)(zr + kt * 32 + 4);
    }
    tc[mt] = tin[row0 + mt * 16 + l15];
  }

  auto ldh = [&](int off) -> short8 {   // 8B-aligned LDS read of 8 shorts
    short4v a = *(const short4v*)&hbuf[off];
    short4v b = *(const short4v*)&hbuf[off + 4];
    return __builtin_shufflevector(a, b, 0, 1, 2, 3, 4, 5, 6, 7);
  };

  // ---- build A fragments ----
  short8 XA[2][6];
#pragma unroll
  for (int mt = 0; mt < 2; mt++)
#pragma unroll
    for (int kt = 0; kt < 6; kt++) {
      union { short8 s; __hip_bfloat162 h[4]; } u;
      f32x4 a = zc[mt][kt][0], b = zc[mt][kt][1];
      u.h[0] = __float22bfloat162_rn(make_float2(a[0], a[1]));
      u.h[1] = __float22bfloat162_rn(make_float2(a[2], a[3]));
      u.h[2] = __float22bfloat162_rn(make_float2(b[0], b[1]));
      u.h[3] = __float22bfloat162_rn(make_float2(b[2], b[3]));
      XA[mt][kt] = u.s;
    }
  float tv0 = tc[0], tv1 = tc[1];

  // ---- Layer 1: [32,192] x [192,112], B-fragments from global (L2) ----
  f32x4 acc[2][7];
#pragma unroll
  for (int nt = 0; nt < 7; nt++) {
    f32x4 zzz = {0.f, 0.f, 0.f, 0.f};
    acc[0][nt] = zzz; acc[1][nt] = zzz;
  }
#pragma unroll
  for (int kt = 0; kt < 6; kt++)
#pragma unroll
    for (int nt = 0; nt < 7; nt++) {
      short8 bf = *(const short8*)(wfrag + (kt * 7 + nt) * 512);
      acc[0][nt] = __builtin_amdgcn_mfma_f32_16x16x32_bf16(XA[0][kt], bf, acc[0][nt], 0, 0, 0);
      acc[1][nt] = __builtin_amdgcn_mfma_f32_16x16x32_bf16(XA[1][kt], bf, acc[1][nt], 0, 0, 0);
    }
  // t rank-1 fixup + bias + tanh -> hbuf
  float tr[2][4];
#pragma unroll
  for (int r = 0; r < 4; r++) {
    tr[0][r] = __shfl(tv0, qd * 4 + r);
    tr[1][r] = __shfl(tv1, qd * 4 + r);
  }
#pragma unroll
  for (int mt = 0; mt < 2; mt++)
#pragma unroll
    for (int nt = 0; nt < 7; nt++)
#pragma unroll
      for (int r = 0; r < 4; r++) {
        float v = fmaf(tr[mt][r], w0v[nt], acc[mt][nt][r] + b1v[nt]);
        hbuf[hb + (mt * 16 + qd * 4 + r) * HST + nt * 16 + l15] = (short)f2bf(tanh_fast(v));
      }

  // ---- Layer 2: [32,128] x [128,112] (kt=3: K rows 112..127 are B-zero) ----
  short8 HA[2][4];
#pragma unroll
  for (int mt = 0; mt < 2; mt++) {
    int ro = hb + (mt * 16 + l15) * HST;
#pragma unroll
    for (int kt = 0; kt < 3; kt++) HA[mt][kt] = ldh(ro + kt * 32 + qd * 8);
    HA[mt][3] = ldh(ro + 96 + (qd & 1) * 8);  // qd>=2 garbage x B-zero = 0
  }
#pragma unroll
  for (int nt = 0; nt < 7; nt++) {
    f32x4 zzz = {0.f, 0.f, 0.f, 0.f};
    acc[0][nt] = zzz; acc[1][nt] = zzz;
  }
#pragma unroll
  for (int kt = 0; kt < 4; kt++)
#pragma unroll
    for (int nt = 0; nt < 7; nt++) {
      short8 bf = *(const short8*)(wfrag + (42 + kt * 7 + nt) * 512);
      acc[0][nt] = __builtin_amdgcn_mfma_f32_16x16x32_bf16(HA[0][kt], bf, acc[0][nt], 0, 0, 0);
      acc[1][nt] = __builtin_amdgcn_mfma_f32_16x16x32_bf16(HA[1][kt], bf, acc[1][nt], 0, 0, 0);
    }
#pragma unroll
  for (int mt = 0; mt < 2; mt++)
#pragma unroll
    for (int nt = 0; nt < 7; nt++)
#pragma unroll
      for (int r = 0; r < 4; r++) {
        float v = acc[mt][nt][r] + b2v[nt];
        hbuf[hb + (mt * 16 + qd * 4 + r) * HST + nt * 16 + l15] = (short)f2bf(tanh_fast(v));
      }

  // ---- Layer 3 (scatter-folded): [32,128] x [128,96] -> q ----
#pragma unroll
  for (int mt = 0; mt < 2; mt++) {
    int ro = hb + (mt * 16 + l15) * HST;
#pragma unroll
    for (int kt = 0; kt < 3; kt++) HA[mt][kt] = ldh(ro + kt * 32 + qd * 8);
    HA[mt][3] = ldh(ro + 96 + (qd & 1) * 8);
  }
  f32x4 qa[2][6];
#pragma unroll
  for (int nt = 0; nt < 6; nt++) {
    f32x4 zzz = {0.f, 0.f, 0.f, 0.f};
    qa[0][nt] = zzz; qa[1][nt] = zzz;
  }
#pragma unroll
  for (int kt = 0; kt < 4; kt++)
#pragma unroll
    for (int nt = 0; nt < 6; nt++) {
      short8 bf = *(const short8*)(wfrag + (70 + kt * 6 + nt) * 512);
      qa[0][nt] = __builtin_amdgcn_mfma_f32_16x16x32_bf16(HA[0][kt], bf, qa[0][nt], 0, 0, 0);
      qa[1][nt] = __builtin_amdgcn_mfma_f32_16x16x32_bf16(HA[1][kt], bf, qa[1][nt], 0, 0, 0);
    }

  // ---- QP epilogue ----
#pragma unroll
  for (int mt = 0; mt < 2; mt++) {
#pragma unroll
    for (int nt = 0; nt < 6; nt++) {
      float bq = bqv[nt];
      qa[mt][nt][0] += bq; qa[mt][nt][1] += bq;
      qa[mt][nt][2] += bq; qa[mt][nt][3] += bq;
    }
    f32x4 rs = {0.f, 0.f, 0.f, 0.f};
#pragma unroll
    for (int nt = 0; nt < 6; nt++) rs += qa[mt][nt] * qa[mt][nt];
    float rv[4];
#pragma unroll
    for (int r = 0; r < 4; r++) {
      float v = rs[r];
      v += __shfl_xor(v, 1);
      v += __shfl_xor(v, 2);
      v += __shfl_xor(v, 4);
      v += __shfl_xor(v, 8);
      rv[r] = v;
    }
    float r2 = rv[l15 & 3];
    float s = __builtin_amdgcn_exp2f(__builtin_amdgcn_logf(r2) * 0.333333333333f);
#pragma unroll
    for (int itn = 0; itn < 8; itn++) {
      float one = 1.f + s;
      float fv = fmaf(s * one, one, -r2);
      float fp = one * fmaf(2.f, s, one);
      s = fmaxf(s - fv * __builtin_amdgcn_rcpf(fp), 0.f);
    }
    float myinv = -__builtin_amdgcn_rcpf(1.f + s);
#pragma unroll
    for (int r = 0; r < 4; r++) {
      float inv = __shfl(myinv, (lane & 48) | r);
      float* orow = out + (size_t)(row0 + mt * 16 + qd * 4 + r) * 96;
#pragma unroll
      for (int nt = 0; nt < 6; nt++)
        orow[nt * 16 + l15] = qa[mt][nt][r] * inv;
    }
  }
}

extern "C" void kernel_launch(void* const* d_in, const int* in_sizes, int n_in,
                              void* d_out, int out_size, void* d_ws, size_t ws_size,
                              hipStream_t stream) {
  const float* z  = (const float*)d_in[0];
  const float* t  = (const float*)d_in[1];
  const float* W1 = (const float*)d_in[2];
  const float* b1 = (const float*)d_in[3];
  const float* W2 = (const float*)d_in[4];
  const float* b2 = (const float*)d_in[5];
  const float* W3 = (const float*)d_in[6];
  const float* b3 = (const float*)d_in[7];
  float* out = (float*)d_out;
  int B = in_sizes[0] / 192;                 // 131072

  short* pw = (short*)d_ws;                  // 97,984 bytes used
  cvx_prep<<<190, 256, 0, stream>>>(W1, b1, W2, b2, W3, b3, pw);
  cvx_main<<<B / 256, 512, 0, stream>>>(z, t, pw, out);
}

// Round 3
// 196.164 us; speedup vs baseline: 1.3606x; 1.0153x over previous
//
#include <hip/hip_runtime.h>
#include <hip/hip_bf16.h>

// ---------------------------------------------------------------------------
// CVXPolicy_DoubleIntegrator, R5: R4 (weights-from-L2, hbuf-only LDS,
// 2 blocks/CU) with the launch-bounds fix.
//
// R4 post-mortem: __launch_bounds__ 2nd arg behaves as min BLOCKS/CU (CUDA
// semantics) on this compiler: (512,4) -> 32 waves/CU -> VGPR cap 64 -> spill
// (WRITE_SIZE +15MB). (512,2) caps at 128 VGPR, which this per-wave structure
// fits with zero spill (proven R2). LDS = 59KB -> 2 blocks/CU co-resident,
// 16 waves/CU, barrier-free so waves desync and overlap HBM/VALU/MFMA phases.
//
// Packed weights (bf16, scatter folded into W3, t-row of W1 removed):
//   PW1: frag (kt*7+nt), kt<6, nt<7        -> shorts [0, 21504)
//   PW2: frag 42+kt*7+nt, kt<4, nt<7       -> shorts [21504, 35840)
//   PW3: frag 70+kt*6+nt, kt<4, nt<6       -> shorts [35840, 48128)
//   floats at short-index 48128: w0[112], b1[112], b2[112], bq[96]
// frag = 512 shorts: element e = lane*8+j -> B[k = kt*32+(lane>>4)*8+j][n = nt*16+(lane&15)]
//
// MFMA 16x16x32 bf16 layouts (verified in R1, passed):
//   A:   lane -> A[m = lane&15][k = (lane>>4)*8 + j]
//   C/D: lane -> col = lane&15, row = (lane>>4)*4 + reg
// ---------------------------------------------------------------------------

typedef __attribute__((ext_vector_type(8))) short short8;
typedef __attribute__((ext_vector_type(4))) short short4v;
typedef __attribute__((ext_vector_type(4))) float f32x4;

#define HST 116  // hbuf row stride in shorts (232B: 8B-aligned, uniform banks)

__device__ __forceinline__ unsigned short f2bf(float f) {
  unsigned u = __float_as_uint(f);
  u += 0x7fffu + ((u >> 16) & 1u);  // RNE (finite values only)
  return (unsigned short)(u >> 16);
}
__device__ __forceinline__ float tanh_fast(float x) {
  float ax = fabsf(x);
  float e = __builtin_amdgcn_exp2f(ax * -2.88539008177792681f);  // exp(-2ax)
  float r = (1.f - e) * __builtin_amdgcn_rcpf(1.f + e);
  return copysignf(r, x);
}

// ---------------------------------------------------------------------------
// Prep: pack weights bf16, fold scatter into W3, drop t-row (kept as w0 f32).
// ---------------------------------------------------------------------------
__global__ void cvx_prep(const float* __restrict__ W1, const float* __restrict__ b1,
                         const float* __restrict__ W2, const float* __restrict__ b2,
                         const float* __restrict__ W3, const float* __restrict__ b3,
                         short* __restrict__ pw) {
  int idx = blockIdx.x * 256 + threadIdx.x;

  if (idx < 21504) {                        // PW1: 6 kt * 7 nt * 512
    int kt = idx / 3584, rem = idx % 3584;
    int nt = rem / 512, e = rem % 512;
    int lane = e >> 3, j = e & 7;
    int k = kt * 32 + (lane >> 4) * 8 + j;  // z index; W1 row k+1
    int n = nt * 16 + (lane & 15);
    float wv = (n < 100) ? W1[(k + 1) * 100 + n] : 0.f;
    pw[(kt * 7 + nt) * 512 + e] = (short)f2bf(wv);
    return;
  }
  idx -= 21504;
  if (idx < 14336) {                        // PW2: 4 kt * 7 nt * 512
    int kt = idx / 3584, rem = idx % 3584;
    int nt = rem / 512, e = rem % 512;
    int lane = e >> 3, j = e & 7;
    int k = kt * 32 + (lane >> 4) * 8 + j;
    int n = nt * 16 + (lane & 15);
    float wv = (k < 100 && n < 100) ? W2[k * 100 + n] : 0.f;
    pw[21504 + (kt * 7 + nt) * 512 + e] = (short)f2bf(wv);
    return;
  }
  idx -= 14336;
  if (idx < 12288) {                        // PW3 folded: 4 kt * 6 nt * 512
    int kt = idx / 3072, rem = idx % 3072;
    int nt = rem / 512, e = rem % 512;
    int lane = e >> 3, j = e & 7;
    int k = kt * 32 + (lane >> 4) * 8 + j;
    int u = nt * 16 + (lane & 15);          // u < 96
    float wv = 0.f;
    if (k < 100) {
      const float* wr = W3 + k * 192;
      if (u <= 31) wv += wr[3 * u + 3];                     // u = i
      if ((u & 1) == 0 && u <= 62) wv += wr[2 * u + 4];     // u = 2i
      if (u % 3 == 0 && u <= 93) wv += wr[(5 * u) / 3 + 5]; // u = 3i
    }
    pw[35840 + (kt * 6 + nt) * 512 + e] = (short)f2bf(wv);
    return;
  }
  idx -= 12288;
  float* cb = (float*)(pw + 48128);
  if (idx < 112) { cb[idx] = (idx < 100) ? W1[idx] : 0.f; return; }        // w0 = W1 row 0
  idx -= 112;
  if (idx < 112) { cb[112 + idx] = (idx < 100) ? b1[idx] : 0.f; return; }
  idx -= 112;
  if (idx < 112) { cb[224 + idx] = (idx < 100) ? b2[idx] : 0.f; return; }
  idx -= 112;
  if (idx < 96) {
    int u = idx;
    float v = 0.f;
    if (u <= 31) v += b3[3 * u + 3];
    if ((u & 1) == 0 && u <= 62) v += b3[2 * u + 4];
    if (u % 3 == 0 && u <= 93) v += b3[(5 * u) / 3 + 5];
    cb[336 + u] = v;
  }
}

// ---------------------------------------------------------------------------
// Main fused kernel: 512 thr (8 waves), 256 rows/block (32 rows/wave),
// grid 512 = 2 blocks/CU. No barriers, no weight staging.
// ---------------------------------------------------------------------------
__global__ __launch_bounds__(512, 2) void cvx_main(
    const float* __restrict__ zin, const float* __restrict__ tin,
    const short* __restrict__ pw, float* __restrict__ out) {
  __shared__ __align__(16) short hbuf[8 * 32 * HST];  // 59,392 B: per-wave h

  const int tid = threadIdx.x;
  const int wid = tid >> 6;
  const int lane = tid & 63;
  const int l15 = lane & 15;
  const int qd = lane >> 4;

  // biases / w0 into registers (wave-uniform-per-l15, L2/L3-cached)
  const float* cb = (const float*)(pw + 48128);
  float w0v[7], b1v[7], b2v[7], bqv[6];
#pragma unroll
  for (int nt = 0; nt < 7; nt++) {
    w0v[nt] = cb[nt * 16 + l15];
    b1v[nt] = cb[112 + nt * 16 + l15];
    b2v[nt] = cb[224 + nt * 16 + l15];
  }
#pragma unroll
  for (int nt = 0; nt < 6; nt++) bqv[nt] = cb[336 + nt * 16 + l15];

  const int row0 = blockIdx.x * 256 + wid * 32;
  const int hb = wid * 32 * HST;
  const short* wfrag = pw + lane * 8;  // per-lane base for all B fragments

  // ---- load this wave's 32 rows of z,t ----
  f32x4 zc[2][6][2];
  float tc[2];
#pragma unroll
  for (int mt = 0; mt < 2; mt++) {
    const float* zr = zin + (size_t)(row0 + mt * 16 + l15) * 192 + qd * 8;
#pragma unroll
    for (int kt = 0; kt < 6; kt++) {
      zc[mt][kt][0] = *(const f32x4*)(zr + kt * 32);
      zc[mt][kt][1] = *(const f32x4*)(zr + kt * 32 + 4);
    }
    tc[mt] = tin[row0 + mt * 16 + l15];
  }

  auto ldh = [&](int off) -> short8 {   // 8B-aligned LDS read of 8 shorts
    short4v a = *(const short4v*)&hbuf[off];
    short4v b = *(const short4v*)&hbuf[off + 4];
    return __builtin_shufflevector(a, b, 0, 1, 2, 3, 4, 5, 6, 7);
  };

  // ---- build A fragments ----
  short8 XA[2][6];
#pragma unroll
  for (int mt = 0; mt < 2; mt++)
#pragma unroll
    for (int kt = 0; kt < 6; kt++) {
      union { short8 s; __hip_bfloat162 h[4]; } u;
      f32x4 a = zc[mt][kt][0], b = zc[mt][kt][1];
      u.h[0] = __float22bfloat162_rn(make_float2(a[0], a[1]));
      u.h[1] = __float22bfloat162_rn(make_float2(a[2], a[3]));
      u.h[2] = __float22bfloat162_rn(make_float2(b[0], b[1]));
      u.h[3] = __float22bfloat162_rn(make_float2(b[2], b[3]));
      XA[mt][kt] = u.s;
    }
  float tv0 = tc[0], tv1 = tc[1];

  // ---- Layer 1: [32,192] x [192,112], B-fragments from global (L2) ----
  f32x4 acc[2][7];
#pragma unroll
  for (int nt = 0; nt < 7; nt++) {
    f32x4 zzz = {0.f, 0.f, 0.f, 0.f};
    acc[0][nt] = zzz; acc[1][nt] = zzz;
  }
#pragma unroll
  for (int kt = 0; kt < 6; kt++)
#pragma unroll
    for (int nt = 0; nt < 7; nt++) {
      short8 bf = *(const short8*)(wfrag + (kt * 7 + nt) * 512);
      acc[0][nt] = __builtin_amdgcn_mfma_f32_16x16x32_bf16(XA[0][kt], bf, acc[0][nt], 0, 0, 0);
      acc[1][nt] = __builtin_amdgcn_mfma_f32_16x16x32_bf16(XA[1][kt], bf, acc[1][nt], 0, 0, 0);
    }
  // t rank-1 fixup + bias + tanh -> hbuf
  float tr[2][4];
#pragma unroll
  for (int r = 0; r < 4; r++) {
    tr[0][r] = __shfl(tv0, qd * 4 + r);
    tr[1][r] = __shfl(tv1, qd * 4 + r);
  }
#pragma unroll
  for (int mt = 0; mt < 2; mt++)
#pragma unroll
    for (int nt = 0; nt < 7; nt++)
#pragma unroll
      for (int r = 0; r < 4; r++) {
        float v = fmaf(tr[mt][r], w0v[nt], acc[mt][nt][r] + b1v[nt]);
        hbuf[hb + (mt * 16 + qd * 4 + r) * HST + nt * 16 + l15] = (short)f2bf(tanh_fast(v));
      }

  // ---- Layer 2: [32,128] x [128,112] (kt=3: K rows 112..127 are B-zero) ----
  short8 HA[2][4];
#pragma unroll
  for (int mt = 0; mt < 2; mt++) {
    int ro = hb + (mt * 16 + l15) * HST;
#pragma unroll
    for (int kt = 0; kt < 3; kt++) HA[mt][kt] = ldh(ro + kt * 32 + qd * 8);
    HA[mt][3] = ldh(ro + 96 + (qd & 1) * 8);  // qd>=2 garbage x B-zero = 0
  }
#pragma unroll
  for (int nt = 0; nt < 7; nt++) {
    f32x4 zzz = {0.f, 0.f, 0.f, 0.f};
    acc[0][nt] = zzz; acc[1][nt] = zzz;
  }
#pragma unroll
  for (int kt = 0; kt < 4; kt++)
#pragma unroll
    for (int nt = 0; nt < 7; nt++) {
      short8 bf = *(const short8*)(wfrag + (42 + kt * 7 + nt) * 512);
      acc[0][nt] = __builtin_amdgcn_mfma_f32_16x16x32_bf16(HA[0][kt], bf, acc[0][nt], 0, 0, 0);
      acc[1][nt] = __builtin_amdgcn_mfma_f32_16x16x32_bf16(HA[1][kt], bf, acc[1][nt], 0, 0, 0);
    }
#pragma unroll
  for (int mt = 0; mt < 2; mt++)
#pragma unroll
    for (int nt = 0; nt < 7; nt++)
#pragma unroll
      for (int r = 0; r < 4; r++) {
        float v = acc[mt][nt][r] + b2v[nt];
        hbuf[hb + (mt * 16 + qd * 4 + r) * HST + nt * 16 + l15] = (short)f2bf(tanh_fast(v));
      }

  // ---- Layer 3 (scatter-folded): [32,128] x [128,96] -> q ----
#pragma unroll
  for (int mt = 0; mt < 2; mt++) {
    int ro = hb + (mt * 16 + l15) * HST;
#pragma unroll
    for (int kt = 0; kt < 3; kt++) HA[mt][kt] = ldh(ro + kt * 32 + qd * 8);
    HA[mt][3] = ldh(ro + 96 + (qd & 1) * 8);
  }
  f32x4 qa[2][6];
#pragma unroll
  for (int nt = 0; nt < 6; nt++) {
    f32x4 zzz = {0.f, 0.f, 0.f, 0.f};
    qa[0][nt] = zzz; qa[1][nt] = zzz;
  }
#pragma unroll
  for (int kt = 0; kt < 4; kt++)
#pragma unroll
    for (int nt = 0; nt < 6; nt++) {
      short8 bf = *(const short8*)(wfrag + (70 + kt * 6 + nt) * 512);
      qa[0][nt] = __builtin_amdgcn_mfma_f32_16x16x32_bf16(HA[0][kt], bf, qa[0][nt], 0, 0, 0);
      qa[1][nt] = __builtin_amdgcn_mfma_f32_16x16x32_bf16(HA[1][kt], bf, qa[1][nt], 0, 0, 0);
    }

  // ---- QP epilogue ----
#pragma unroll
  for (int mt = 0; mt < 2; mt++) {
#pragma unroll
    for (int nt = 0; nt < 6; nt++) {
      float bq = bqv[nt];
      qa[mt][nt][0] += bq; qa[mt][nt][1] += bq;
      qa[mt][nt][2] += bq; qa[mt][nt][3] += bq;
    }
    f32x4 rs = {0.f, 0.f, 0.f, 0.f};
#pragma unroll
    for (int nt = 0; nt < 6; nt++) rs += qa[mt][nt] * qa[mt][nt];
    float rv[4];
#pragma unroll
    for (int r = 0; r < 4; r++) {
      float v = rs[r];
      v += __shfl_xor(v, 1);
      v += __shfl_xor(v, 2);
      v += __shfl_xor(v, 4);
      v += __shfl_xor(v, 8);
      rv[r] = v;
    }
    float r2 = rv[l15 & 3];
    float s = __builtin_amdgcn_exp2f(__builtin_amdgcn_logf(r2) * 0.333333333333f);
#pragma unroll
    for (int itn = 0; itn < 8; itn++) {
      float one = 1.f + s;
      float fv = fmaf(s * one, one, -r2);
      float fp = one * fmaf(2.f, s, one);
      s = fmaxf(s - fv * __builtin_amdgcn_rcpf(fp), 0.f);
    }
    float myinv = -__builtin_amdgcn_rcpf(1.f + s);
#pragma unroll
    for (int r = 0; r < 4; r++) {
      float inv = __shfl(myinv, (lane & 48) | r);
      float* orow = out + (size_t)(row0 + mt * 16 + qd * 4 + r) * 96;
#pragma unroll
      for (int nt = 0; nt < 6; nt++)
        orow[nt * 16 + l15] = qa[mt][nt][r] * inv;
    }
  }
}

extern "C" void kernel_launch(void* const* d_in, const int* in_sizes, int n_in,
                              void* d_out, int out_size, void* d_ws, size_t ws_size,
                              hipStream_t stream) {
  const float* z  = (const float*)d_in[0];
  const float* t  = (const float*)d_in[1];
  const float* W1 = (const float*)d_in[2];
  const float* b1 = (const float*)d_in[3];
  const float* W2 = (const float*)d_in[4];
  const float* b2 = (const float*)d_in[5];
  const float* W3 = (const float*)d_in[6];
  const float* b3 = (const float*)d_in[7];
  float* out = (float*)d_out;
  int B = in_sizes[0] / 192;                 // 131072

  short* pw = (short*)d_ws;                  // 97,984 bytes used
  cvx_prep<<<190, 256, 0, stream>>>(W1, b1, W2, b2, W3, b3, pw);
  cvx_main<<<B / 256, 512, 0, stream>>>(z, t, pw, out);
}

// Round 4
// 191.676 us; speedup vs baseline: 1.3924x; 1.0234x over previous
//
#include <hip/hip_runtime.h>
#include <hip/hip_bf16.h>

// ---------------------------------------------------------------------------
// CVXPolicy_DoubleIntegrator, R6: R2 base (weights-in-LDS, 1 block/CU,
// barrier-free after staging) + wave PHASE STAGGER + setprio on MFMA.
//
// R3-R5 post-mortem: occupancy is uncorrelated with duration (17%->66.8us,
// 34.5%->73us, 20%->70.9us) and all pipes <21% busy. Theory: waves run the
// identical phase sequence in lockstep, so memory-wait phases of all waves
// coincide and co-residency cannot hide them. R6 staggers: odd waves process
// their two 256-row tiles in reverse order, so the 2 waves/SIMD are always
// ~1 tile-phase apart (one in tanh/VALU while the other is in MFMA/memory).
// s_setprio(1) wraps MFMA nests (T5: pays only with wave role diversity,
// which the stagger now creates).
//
// Packed weights (bf16, scatter folded into W3, t-row of W1 removed):
//   PW1: frag (kt*7+nt), kt<6, nt<7        -> shorts [0, 21504)
//   PW2: frag 42+kt*7+nt, kt<4, nt<7       -> shorts [21504, 35840)
//   PW3: frag 70+kt*6+nt, kt<4, nt<6       -> shorts [35840, 48128)
//   floats at short-index 48128: w0[112], b1[112], b2[112], bq[96]
// frag = 512 shorts: element e = lane*8+j -> B[k = kt*32+(lane>>4)*8+j][n = nt*16+(lane&15)]
//
// MFMA 16x16x32 bf16 layouts (verified in R1, passed):
//   A:   lane -> A[m = lane&15][k = (lane>>4)*8 + j]
//   C/D: lane -> col = lane&15, row = (lane>>4)*4 + reg
// ---------------------------------------------------------------------------

typedef __attribute__((ext_vector_type(8))) short short8;
typedef __attribute__((ext_vector_type(4))) short short4v;
typedef __attribute__((ext_vector_type(4))) float f32x4;

#define HST 116  // hbuf row stride in shorts (232B: 8B-aligned, uniform banks)

__device__ __forceinline__ unsigned short f2bf(float f) {
  unsigned u = __float_as_uint(f);
  u += 0x7fffu + ((u >> 16) & 1u);  // RNE (finite values only)
  return (unsigned short)(u >> 16);
}
__device__ __forceinline__ float tanh_fast(float x) {
  float ax = fabsf(x);
  float e = __builtin_amdgcn_exp2f(ax * -2.88539008177792681f);  // exp(-2ax)
  float r = (1.f - e) * __builtin_amdgcn_rcpf(1.f + e);
  return copysignf(r, x);
}

// ---------------------------------------------------------------------------
// Prep: pack weights bf16, fold scatter into W3, drop t-row (kept as w0 f32).
// ---------------------------------------------------------------------------
__global__ void cvx_prep(const float* __restrict__ W1, const float* __restrict__ b1,
                         const float* __restrict__ W2, const float* __restrict__ b2,
                         const float* __restrict__ W3, const float* __restrict__ b3,
                         short* __restrict__ pw) {
  int idx = blockIdx.x * 256 + threadIdx.x;

  if (idx < 21504) {                        // PW1: 6 kt * 7 nt * 512
    int kt = idx / 3584, rem = idx % 3584;
    int nt = rem / 512, e = rem % 512;
    int lane = e >> 3, j = e & 7;
    int k = kt * 32 + (lane >> 4) * 8 + j;  // z index; W1 row k+1
    int n = nt * 16 + (lane & 15);
    float wv = (n < 100) ? W1[(k + 1) * 100 + n] : 0.f;
    pw[(kt * 7 + nt) * 512 + e] = (short)f2bf(wv);
    return;
  }
  idx -= 21504;
  if (idx < 14336) {                        // PW2: 4 kt * 7 nt * 512
    int kt = idx / 3584, rem = idx % 3584;
    int nt = rem / 512, e = rem % 512;
    int lane = e >> 3, j = e & 7;
    int k = kt * 32 + (lane >> 4) * 8 + j;
    int n = nt * 16 + (lane & 15);
    float wv = (k < 100 && n < 100) ? W2[k * 100 + n] : 0.f;
    pw[21504 + (kt * 7 + nt) * 512 + e] = (short)f2bf(wv);
    return;
  }
  idx -= 14336;
  if (idx < 12288) {                        // PW3 folded: 4 kt * 6 nt * 512
    int kt = idx / 3072, rem = idx % 3072;
    int nt = rem / 512, e = rem % 512;
    int lane = e >> 3, j = e & 7;
    int k = kt * 32 + (lane >> 4) * 8 + j;
    int u = nt * 16 + (lane & 15);          // u < 96
    float wv = 0.f;
    if (k < 100) {
      const float* wr = W3 + k * 192;
      if (u <= 31) wv += wr[3 * u + 3];                     // u = i
      if ((u & 1) == 0 && u <= 62) wv += wr[2 * u + 4];     // u = 2i
      if (u % 3 == 0 && u <= 93) wv += wr[(5 * u) / 3 + 5]; // u = 3i
    }
    pw[35840 + (kt * 6 + nt) * 512 + e] = (short)f2bf(wv);
    return;
  }
  idx -= 12288;
  float* cb = (float*)(pw + 48128);
  if (idx < 112) { cb[idx] = (idx < 100) ? W1[idx] : 0.f; return; }        // w0 = W1 row 0
  idx -= 112;
  if (idx < 112) { cb[112 + idx] = (idx < 100) ? b1[idx] : 0.f; return; }
  idx -= 112;
  if (idx < 112) { cb[224 + idx] = (idx < 100) ? b2[idx] : 0.f; return; }
  idx -= 112;
  if (idx < 96) {
    int u = idx;
    float v = 0.f;
    if (u <= 31) v += b3[3 * u + 3];
    if ((u & 1) == 0 && u <= 62) v += b3[2 * u + 4];
    if (u % 3 == 0 && u <= 93) v += b3[(5 * u) / 3 + 5];
    cb[336 + u] = v;
  }
}

// ---------------------------------------------------------------------------
// Main fused kernel: 512 thr (8 waves), 1 block/CU (grid 256), 2 tiles x 256
// rows per wave, tile ORDER staggered by wave parity.
// ---------------------------------------------------------------------------
__global__ __launch_bounds__(512, 2) void cvx_main(
    const float* __restrict__ zin, const float* __restrict__ tin,
    const short* __restrict__ pw, float* __restrict__ out) {
  __shared__ __align__(16) short wbuf[48128];        // 96,256 B: all weights
  __shared__ __align__(16) short hbuf[8 * 32 * HST]; // 59,392 B: per-wave h

  const int tid = threadIdx.x;
  const int wid = tid >> 6;
  const int lane = tid & 63;
  const int l15 = lane & 15;
  const int qd = lane >> 4;
  const int myt0 = wid & 1;   // phase stagger: odd waves do tile 1 first

  // stage ALL weights into LDS (once per block)
  for (int f = wid; f < 94; f += 8) {
    const short* g = pw + f * 512 + lane * 8;
    __builtin_amdgcn_global_load_lds(
        (const __attribute__((address_space(1))) void*)g,
        (__attribute__((address_space(3))) void*)&wbuf[f * 512], 16, 0, 0);
  }

  // biases / w0 into registers (constant across tiles)
  const float* cb = (const float*)(pw + 48128);
  float w0v[7], b1v[7], b2v[7], bqv[6];
#pragma unroll
  for (int nt = 0; nt < 7; nt++) {
    w0v[nt] = cb[nt * 16 + l15];
    b1v[nt] = cb[112 + nt * 16 + l15];
    b2v[nt] = cb[224 + nt * 16 + l15];
  }
#pragma unroll
  for (int nt = 0; nt < 6; nt++) bqv[nt] = cb[336 + nt * 16 + l15];

  const int row0 = blockIdx.x * 512 + wid * 32;
  const int hb = wid * 32 * HST;

  // prefetch FIRST tile (stagger-dependent) z,t into registers
  f32x4 zc[2][6][2];
  float tc[2];
#pragma unroll
  for (int mt = 0; mt < 2; mt++) {
    const float* zr = zin + (size_t)(row0 + myt0 * 256 + mt * 16 + l15) * 192 + qd * 8;
#pragma unroll
    for (int kt = 0; kt < 6; kt++) {
      zc[mt][kt][0] = *(const f32x4*)(zr + kt * 32);
      zc[mt][kt][1] = *(const f32x4*)(zr + kt * 32 + 4);
    }
    tc[mt] = tin[row0 + myt0 * 256 + mt * 16 + l15];
  }

  __syncthreads();  // the only barrier: weights resident from here on

  auto ldh = [&](int off) -> short8 {   // 8B-aligned LDS read of 8 shorts
    short4v a = *(const short4v*)&hbuf[off];
    short4v b = *(const short4v*)&hbuf[off + 4];
    return __builtin_shufflevector(a, b, 0, 1, 2, 3, 4, 5, 6, 7);
  };

#pragma unroll 1
  for (int ii = 0; ii < 2; ++ii) {
    const int it = ii ^ myt0;           // staggered tile index
    const int rb = row0 + it * 256;

    // ---- build A fragments from prefetched z ----
    short8 XA[2][6];
#pragma unroll
    for (int mt = 0; mt < 2; mt++)
#pragma unroll
      for (int kt = 0; kt < 6; kt++) {
        union { short8 s; __hip_bfloat162 h[4]; } u;
        f32x4 a = zc[mt][kt][0], b = zc[mt][kt][1];
        u.h[0] = __float22bfloat162_rn(make_float2(a[0], a[1]));
        u.h[1] = __float22bfloat162_rn(make_float2(a[2], a[3]));
        u.h[2] = __float22bfloat162_rn(make_float2(b[0], b[1]));
        u.h[3] = __float22bfloat162_rn(make_float2(b[2], b[3]));
        XA[mt][kt] = u.s;
      }
    float tv0 = tc[0], tv1 = tc[1];

    // ---- prefetch the OTHER tile while this one computes ----
    if (ii == 0) {
      const int ot = it ^ 1;
#pragma unroll
      for (int mt = 0; mt < 2; mt++) {
        const float* zr = zin + (size_t)(row0 + ot * 256 + mt * 16 + l15) * 192 + qd * 8;
#pragma unroll
        for (int kt = 0; kt < 6; kt++) {
          zc[mt][kt][0] = *(const f32x4*)(zr + kt * 32);
          zc[mt][kt][1] = *(const f32x4*)(zr + kt * 32 + 4);
        }
        tc[mt] = tin[row0 + ot * 256 + mt * 16 + l15];
      }
    }

    // ---- Layer 1: [32,192] x [192,112] ----
    f32x4 acc[2][7];
#pragma unroll
    for (int nt = 0; nt < 7; nt++) {
      f32x4 zzz = {0.f, 0.f, 0.f, 0.f};
      acc[0][nt] = zzz; acc[1][nt] = zzz;
    }
    __builtin_amdgcn_s_setprio(1);
#pragma unroll
    for (int kt = 0; kt < 6; kt++)
#pragma unroll
      for (int nt = 0; nt < 7; nt++) {
        short8 bf = *(const short8*)&wbuf[(kt * 7 + nt) * 512 + lane * 8];
        acc[0][nt] = __builtin_amdgcn_mfma_f32_16x16x32_bf16(XA[0][kt], bf, acc[0][nt], 0, 0, 0);
        acc[1][nt] = __builtin_amdgcn_mfma_f32_16x16x32_bf16(XA[1][kt], bf, acc[1][nt], 0, 0, 0);
      }
    __builtin_amdgcn_s_setprio(0);
    // t rank-1 fixup + bias + tanh -> hbuf
    float tr[2][4];
#pragma unroll
    for (int r = 0; r < 4; r++) {
      tr[0][r] = __shfl(tv0, qd * 4 + r);
      tr[1][r] = __shfl(tv1, qd * 4 + r);
    }
#pragma unroll
    for (int mt = 0; mt < 2; mt++)
#pragma unroll
      for (int nt = 0; nt < 7; nt++)
#pragma unroll
        for (int r = 0; r < 4; r++) {
          float v = fmaf(tr[mt][r], w0v[nt], acc[mt][nt][r] + b1v[nt]);
          hbuf[hb + (mt * 16 + qd * 4 + r) * HST + nt * 16 + l15] = (short)f2bf(tanh_fast(v));
        }

    // ---- Layer 2: [32,128] x [128,112] (kt=3: K rows 112..127 are B-zero) ----
    short8 HA[2][4];
#pragma unroll
    for (int mt = 0; mt < 2; mt++) {
      int ro = hb + (mt * 16 + l15) * HST;
#pragma unroll
      for (int kt = 0; kt < 3; kt++) HA[mt][kt] = ldh(ro + kt * 32 + qd * 8);
      HA[mt][3] = ldh(ro + 96 + (qd & 1) * 8);  // qd>=2 garbage x B-zero = 0
    }
#pragma unroll
    for (int nt = 0; nt < 7; nt++) {
      f32x4 zzz = {0.f, 0.f, 0.f, 0.f};
      acc[0][nt] = zzz; acc[1][nt] = zzz;
    }
    __builtin_amdgcn_s_setprio(1);
#pragma unroll
    for (int kt = 0; kt < 4; kt++)
#pragma unroll
      for (int nt = 0; nt < 7; nt++) {
        short8 bf = *(const short8*)&wbuf[(42 + kt * 7 + nt) * 512 + lane * 8];
        acc[0][nt] = __builtin_amdgcn_mfma_f32_16x16x32_bf16(HA[0][kt], bf, acc[0][nt], 0, 0, 0);
        acc[1][nt] = __builtin_amdgcn_mfma_f32_16x16x32_bf16(HA[1][kt], bf, acc[1][nt], 0, 0, 0);
      }
    __builtin_amdgcn_s_setprio(0);
#pragma unroll
    for (int mt = 0; mt < 2; mt++)
#pragma unroll
      for (int nt = 0; nt < 7; nt++)
#pragma unroll
        for (int r = 0; r < 4; r++) {
          float v = acc[mt][nt][r] + b2v[nt];
          hbuf[hb + (mt * 16 + qd * 4 + r) * HST + nt * 16 + l15] = (short)f2bf(tanh_fast(v));
        }

    // ---- Layer 3 (scatter-folded): [32,128] x [128,96] -> q ----
#pragma unroll
    for (int mt = 0; mt < 2; mt++) {
      int ro = hb + (mt * 16 + l15) * HST;
#pragma unroll
      for (int kt = 0; kt < 3; kt++) HA[mt][kt] = ldh(ro + kt * 32 + qd * 8);
      HA[mt][3] = ldh(ro + 96 + (qd & 1) * 8);
    }
    f32x4 qa[2][6];
#pragma unroll
    for (int nt = 0; nt < 6; nt++) {
      f32x4 zzz = {0.f, 0.f, 0.f, 0.f};
      qa[0][nt] = zzz; qa[1][nt] = zzz;
    }
    __builtin_amdgcn_s_setprio(1);
#pragma unroll
    for (int kt = 0; kt < 4; kt++)
#pragma unroll
      for (int nt = 0; nt < 6; nt++) {
        short8 bf = *(const short8*)&wbuf[(70 + kt * 6 + nt) * 512 + lane * 8];
        qa[0][nt] = __builtin_amdgcn_mfma_f32_16x16x32_bf16(HA[0][kt], bf, qa[0][nt], 0, 0, 0);
        qa[1][nt] = __builtin_amdgcn_mfma_f32_16x16x32_bf16(HA[1][kt], bf, qa[1][nt], 0, 0, 0);
      }
    __builtin_amdgcn_s_setprio(0);

    // ---- QP epilogue ----
#pragma unroll
    for (int mt = 0; mt < 2; mt++) {
#pragma unroll
      for (int nt = 0; nt < 6; nt++) {
        float bq = bqv[nt];
        qa[mt][nt][0] += bq; qa[mt][nt][1] += bq;
        qa[mt][nt][2] += bq; qa[mt][nt][3] += bq;
      }
      f32x4 rs = {0.f, 0.f, 0.f, 0.f};
#pragma unroll
      for (int nt = 0; nt < 6; nt++) rs += qa[mt][nt] * qa[mt][nt];
      float rv[4];
#pragma unroll
      for (int r = 0; r < 4; r++) {
        float v = rs[r];
        v += __shfl_xor(v, 1);
        v += __shfl_xor(v, 2);
        v += __shfl_xor(v, 4);
        v += __shfl_xor(v, 8);
        rv[r] = v;
      }
      float r2 = rv[l15 & 3];
      float s = __builtin_amdgcn_exp2f(__builtin_amdgcn_logf(r2) * 0.333333333333f);
#pragma unroll
      for (int itn = 0; itn < 8; itn++) {
        float one = 1.f + s;
        float fv = fmaf(s * one, one, -r2);
        float fp = one * fmaf(2.f, s, one);
        s = fmaxf(s - fv * __builtin_amdgcn_rcpf(fp), 0.f);
      }
      float myinv = -__builtin_amdgcn_rcpf(1.f + s);
#pragma unroll
      for (int r = 0; r < 4; r++) {
        float inv = __shfl(myinv, (lane & 48) | r);
        float* orow = out + (size_t)(rb + mt * 16 + qd * 4 + r) * 96;
#pragma unroll
        for (int nt = 0; nt < 6; nt++)
          orow[nt * 16 + l15] = qa[mt][nt][r] * inv;
      }
    }
  }
}

extern "C" void kernel_launch(void* const* d_in, const int* in_sizes, int n_in,
                              void* d_out, int out_size, void* d_ws, size_t ws_size,
                              hipStream_t stream) {
  const float* z  = (const float*)d_in[0];
  const float* t  = (const float*)d_in[1];
  const float* W1 = (const float*)d_in[2];
  const float* b1 = (const float*)d_in[3];
  const float* W2 = (const float*)d_in[4];
  const float* b2 = (const float*)d_in[5];
  const float* W3 = (const float*)d_in[6];
  const float* b3 = (const float*)d_in[7];
  float* out = (float*)d_out;
  int B = in_sizes[0] / 192;                 // 131072

  short* pw = (short*)d_ws;                  // 97,984 bytes used
  cvx_prep<<<190, 256, 0, stream>>>(W1, b1, W2, b2, W3, b3, pw);
  cvx_main<<<B / 512, 512, 0, stream>>>(z, t, pw, out);
}

// Round 5
// 190.653 us; speedup vs baseline: 1.3999x; 1.0054x over previous
//
#include <hip/hip_runtime.h>
#include <hip/hip_bf16.h>

// ---------------------------------------------------------------------------
// CVXPolicy_DoubleIntegrator, R7: R2 base + REAL tile-1 prefetch.
//
// R2-R6 post-mortem: all variants 65-74us; VALU 13us + MFMA 5us + HBM 18us
// should overlap to ~25us but don't. Register arithmetic shows R2's tile-1 z
// "prefetch" (48 f32 VGPRs) + acc(56) + biases(27) + HA(16) > 128 cap, yet
// WRITE_SIZE shows zero spill => the allocator SANK the prefetch loads to
// their use, serializing a ~50MB chip-wide z wait into each tile. R7 makes
// the prefetch survive: biases->LDS (frees 27 regs), prefetch converted to
// bf16 A-frags (XN, 24 regs) in 3 groups of 32 transient f32 regs spread
// through tile-0's L1 phase; sched_barrier pins issue points; tile-0 XA is
// packed pre-barrier (the barrier's vmcnt(0) covers it).
//
// Packed weights (bf16, scatter folded into W3, t-row of W1 removed):
//   PW1: frag (kt*7+nt), kt<6, nt<7        -> shorts [0, 21504)
//   PW2: frag 42+kt*7+nt, kt<4, nt<7       -> shorts [21504, 35840)
//   PW3: frag 70+kt*6+nt, kt<4, nt<6       -> shorts [35840, 48128)
//   floats at short-index 48128: w0[112], b1[112], b2[112], bq[96]
// frag = 512 shorts: element e = lane*8+j -> B[k = kt*32+(lane>>4)*8+j][n = nt*16+(lane&15)]
//
// MFMA 16x16x32 bf16 layouts (verified in R1, passed):
//   A:   lane -> A[m = lane&15][k = (lane>>4)*8 + j]
//   C/D: lane -> col = lane&15, row = (lane>>4)*4 + reg
// ---------------------------------------------------------------------------

typedef __attribute__((ext_vector_type(8))) short short8;
typedef __attribute__((ext_vector_type(4))) short short4v;
typedef __attribute__((ext_vector_type(4))) float f32x4;

#define HST 116  // hbuf row stride in shorts (232B: 8B-aligned, uniform banks)

__device__ __forceinline__ unsigned short f2bf(float f) {
  unsigned u = __float_as_uint(f);
  u += 0x7fffu + ((u >> 16) & 1u);  // RNE (finite values only)
  return (unsigned short)(u >> 16);
}
__device__ __forceinline__ float tanh_fast(float x) {
  float ax = fabsf(x);
  float e = __builtin_amdgcn_exp2f(ax * -2.88539008177792681f);  // exp(-2ax)
  float r = (1.f - e) * __builtin_amdgcn_rcpf(1.f + e);
  return copysignf(r, x);
}
__device__ __forceinline__ short8 pack_bf8(f32x4 a, f32x4 b) {
  union { short8 s; __hip_bfloat162 h[4]; } u;
  u.h[0] = __float22bfloat162_rn(make_float2(a[0], a[1]));
  u.h[1] = __float22bfloat162_rn(make_float2(a[2], a[3]));
  u.h[2] = __float22bfloat162_rn(make_float2(b[0], b[1]));
  u.h[3] = __float22bfloat162_rn(make_float2(b[2], b[3]));
  return u.s;
}

// ---------------------------------------------------------------------------
// Prep: pack weights bf16, fold scatter into W3, drop t-row (kept as w0 f32).
// ---------------------------------------------------------------------------
__global__ void cvx_prep(const float* __restrict__ W1, const float* __restrict__ b1,
                         const float* __restrict__ W2, const float* __restrict__ b2,
                         const float* __restrict__ W3, const float* __restrict__ b3,
                         short* __restrict__ pw) {
  int idx = blockIdx.x * 256 + threadIdx.x;

  if (idx < 21504) {                        // PW1: 6 kt * 7 nt * 512
    int kt = idx / 3584, rem = idx % 3584;
    int nt = rem / 512, e = rem % 512;
    int lane = e >> 3, j = e & 7;
    int k = kt * 32 + (lane >> 4) * 8 + j;  // z index; W1 row k+1
    int n = nt * 16 + (lane & 15);
    float wv = (n < 100) ? W1[(k + 1) * 100 + n] : 0.f;
    pw[(kt * 7 + nt) * 512 + e] = (short)f2bf(wv);
    return;
  }
  idx -= 21504;
  if (idx < 14336) {                        // PW2: 4 kt * 7 nt * 512
    int kt = idx / 3584, rem = idx % 3584;
    int nt = rem / 512, e = rem % 512;
    int lane = e >> 3, j = e & 7;
    int k = kt * 32 + (lane >> 4) * 8 + j;
    int n = nt * 16 + (lane & 15);
    float wv = (k < 100 && n < 100) ? W2[k * 100 + n] : 0.f;
    pw[21504 + (kt * 7 + nt) * 512 + e] = (short)f2bf(wv);
    return;
  }
  idx -= 14336;
  if (idx < 12288) {                        // PW3 folded: 4 kt * 6 nt * 512
    int kt = idx / 3072, rem = idx % 3072;
    int nt = rem / 512, e = rem % 512;
    int lane = e >> 3, j = e & 7;
    int k = kt * 32 + (lane >> 4) * 8 + j;
    int u = nt * 16 + (lane & 15);          // u < 96
    float wv = 0.f;
    if (k < 100) {
      const float* wr = W3 + k * 192;
      if (u <= 31) wv += wr[3 * u + 3];                     // u = i
      if ((u & 1) == 0 && u <= 62) wv += wr[2 * u + 4];     // u = 2i
      if (u % 3 == 0 && u <= 93) wv += wr[(5 * u) / 3 + 5]; // u = 3i
    }
    pw[35840 + (kt * 6 + nt) * 512 + e] = (short)f2bf(wv);
    return;
  }
  idx -= 12288;
  float* cb = (float*)(pw + 48128);
  if (idx < 112) { cb[idx] = (idx < 100) ? W1[idx] : 0.f; return; }        // w0 = W1 row 0
  idx -= 112;
  if (idx < 112) { cb[112 + idx] = (idx < 100) ? b1[idx] : 0.f; return; }
  idx -= 112;
  if (idx < 112) { cb[224 + idx] = (idx < 100) ? b2[idx] : 0.f; return; }
  idx -= 112;
  if (idx < 96) {
    int u = idx;
    float v = 0.f;
    if (u <= 31) v += b3[3 * u + 3];
    if ((u & 1) == 0 && u <= 62) v += b3[2 * u + 4];
    if (u % 3 == 0 && u <= 93) v += b3[(5 * u) / 3 + 5];
    cb[336 + u] = v;
  }
}

// ---------------------------------------------------------------------------
// Main fused kernel: 512 thr (8 waves), 1 block/CU (grid 256), 2 tiles x 256
// rows per wave, pipelined z prefetch (bf16-packed) for tile 1.
// ---------------------------------------------------------------------------
__global__ __launch_bounds__(512, 2) void cvx_main(
    const float* __restrict__ zin, const float* __restrict__ tin,
    const short* __restrict__ pw, float* __restrict__ out) {
  __shared__ __align__(16) short wbuf[48128];        // 96,256 B: all weights
  __shared__ __align__(16) short hbuf[8 * 32 * HST]; // 59,392 B: per-wave h
  __shared__ __align__(16) float cbl[448];           // 1,792 B: w0|b1|b2|bq

  const int tid = threadIdx.x;
  const int wid = tid >> 6;
  const int lane = tid & 63;
  const int l15 = lane & 15;
  const int qd = lane >> 4;

  // stage ALL weights into LDS (once per block)
  for (int f = wid; f < 94; f += 8) {
    const short* g = pw + f * 512 + lane * 8;
    __builtin_amdgcn_global_load_lds(
        (const __attribute__((address_space(1))) void*)g,
        (__attribute__((address_space(3))) void*)&wbuf[f * 512], 16, 0, 0);
  }
  // stage bias/w0 block into LDS (f32); barrier below covers visibility
  if (tid < 448) cbl[tid] = ((const float*)(pw + 48128))[tid];

  const int row0 = blockIdx.x * 512 + wid * 32;
  const int hb = wid * 32 * HST;

  // tile-0 z,t -> bf16 A-fragments, pre-barrier (overlaps weight staging;
  // the barrier's vmcnt(0)/lgkmcnt(0) drain covers these loads anyway).
  short8 XA[2][6];
  float tc0, tc1;
#pragma unroll
  for (int mt = 0; mt < 2; mt++) {
    const float* zr = zin + (size_t)(row0 + mt * 16 + l15) * 192 + qd * 8;
#pragma unroll
    for (int kt = 0; kt < 6; kt++) {
      f32x4 a = *(const f32x4*)(zr + kt * 32);
      f32x4 b = *(const f32x4*)(zr + kt * 32 + 4);
      XA[mt][kt] = pack_bf8(a, b);
    }
  }
  tc0 = tin[row0 + l15];
  tc1 = tin[row0 + 16 + l15];

  __syncthreads();  // the only barrier: weights + cbl resident from here on

  auto ldh = [&](int off) -> short8 {   // 8B-aligned LDS read of 8 shorts
    short4v a = *(const short4v*)&hbuf[off];
    short4v b = *(const short4v*)&hbuf[off + 4];
    return __builtin_shufflevector(a, b, 0, 1, 2, 3, 4, 5, 6, 7);
  };

  short8 XN[2][6];   // next-tile A-fragments (built progressively in tile 0)
  float tn0, tn1;

#pragma unroll 1
  for (int ii = 0; ii < 2; ++ii) {
    const int rb = row0 + ii * 256;

    f32x4 acc[2][7];
#pragma unroll
    for (int nt = 0; nt < 7; nt++) {
      f32x4 zzz = {0.f, 0.f, 0.f, 0.f};
      acc[0][nt] = zzz; acc[1][nt] = zzz;
    }

    // staging regs for one prefetch group: [mt][kt-in-pair][half], 32 f32
    f32x4 sg[2][2][2];
    const float* zb = zin + (size_t)(row0 + 256 + l15) * 192 + qd * 8;

    // ---- issue prefetch group 0 (next-tile kt 0,1) ----
    if (ii == 0) {
#pragma unroll
      for (int mt = 0; mt < 2; mt++)
#pragma unroll
        for (int kp = 0; kp < 2; kp++) {
          sg[mt][kp][0] = *(const f32x4*)(zb + mt * 3072 + kp * 32);
          sg[mt][kp][1] = *(const f32x4*)(zb + mt * 3072 + kp * 32 + 4);
        }
      __builtin_amdgcn_sched_barrier(0);
    }

    // ---- Layer 1 kt = 0,1 ----
#pragma unroll
    for (int kt = 0; kt < 2; kt++)
#pragma unroll
      for (int nt = 0; nt < 7; nt++) {
        short8 bf = *(const short8*)&wbuf[(kt * 7 + nt) * 512 + lane * 8];
        acc[0][nt] = __builtin_amdgcn_mfma_f32_16x16x32_bf16(XA[0][kt], bf, acc[0][nt], 0, 0, 0);
        acc[1][nt] = __builtin_amdgcn_mfma_f32_16x16x32_bf16(XA[1][kt], bf, acc[1][nt], 0, 0, 0);
      }

    // ---- pack group 0, issue group 1 (kt 2,3) ----
    if (ii == 0) {
#pragma unroll
      for (int mt = 0; mt < 2; mt++)
#pragma unroll
        for (int kp = 0; kp < 2; kp++)
          XN[mt][kp] = pack_bf8(sg[mt][kp][0], sg[mt][kp][1]);
#pragma unroll
      for (int mt = 0; mt < 2; mt++)
#pragma unroll
        for (int kp = 0; kp < 2; kp++) {
          sg[mt][kp][0] = *(const f32x4*)(zb + mt * 3072 + (2 + kp) * 32);
          sg[mt][kp][1] = *(const f32x4*)(zb + mt * 3072 + (2 + kp) * 32 + 4);
        }
      __builtin_amdgcn_sched_barrier(0);
    }

    // ---- Layer 1 kt = 2,3 ----
#pragma unroll
    for (int kt = 2; kt < 4; kt++)
#pragma unroll
      for (int nt = 0; nt < 7; nt++) {
        short8 bf = *(const short8*)&wbuf[(kt * 7 + nt) * 512 + lane * 8];
        acc[0][nt] = __builtin_amdgcn_mfma_f32_16x16x32_bf16(XA[0][kt], bf, acc[0][nt], 0, 0, 0);
        acc[1][nt] = __builtin_amdgcn_mfma_f32_16x16x32_bf16(XA[1][kt], bf, acc[1][nt], 0, 0, 0);
      }

    // ---- pack group 1, issue group 2 (kt 4,5 + t); group 2 stays in flight
    //      across the L1 tanh epilogue ----
    if (ii == 0) {
#pragma unroll
      for (int mt = 0; mt < 2; mt++)
#pragma unroll
        for (int kp = 0; kp < 2; kp++)
          XN[mt][2 + kp] = pack_bf8(sg[mt][kp][0], sg[mt][kp][1]);
#pragma unroll
      for (int mt = 0; mt < 2; mt++)
#pragma unroll
        for (int kp = 0; kp < 2; kp++) {
          sg[mt][kp][0] = *(const f32x4*)(zb + mt * 3072 + (4 + kp) * 32);
          sg[mt][kp][1] = *(const f32x4*)(zb + mt * 3072 + (4 + kp) * 32 + 4);
        }
      tn0 = tin[row0 + 256 + l15];
      tn1 = tin[row0 + 256 + 16 + l15];
      __builtin_amdgcn_sched_barrier(0);
    }

    // ---- Layer 1 kt = 4,5 ----
#pragma unroll
    for (int kt = 4; kt < 6; kt++)
#pragma unroll
      for (int nt = 0; nt < 7; nt++) {
        short8 bf = *(const short8*)&wbuf[(kt * 7 + nt) * 512 + lane * 8];
        acc[0][nt] = __builtin_amdgcn_mfma_f32_16x16x32_bf16(XA[0][kt], bf, acc[0][nt], 0, 0, 0);
        acc[1][nt] = __builtin_amdgcn_mfma_f32_16x16x32_bf16(XA[1][kt], bf, acc[1][nt], 0, 0, 0);
      }

    // ---- L1 epilogue: t rank-1 fixup + bias + tanh -> hbuf ----
    float tr[2][4];
#pragma unroll
    for (int r = 0; r < 4; r++) {
      tr[0][r] = __shfl(tc0, qd * 4 + r);
      tr[1][r] = __shfl(tc1, qd * 4 + r);
    }
#pragma unroll
    for (int nt = 0; nt < 7; nt++) {
      float w0v = cbl[nt * 16 + l15];
      float b1v = cbl[112 + nt * 16 + l15];
#pragma unroll
      for (int mt = 0; mt < 2; mt++)
#pragma unroll
        for (int r = 0; r < 4; r++) {
          float v = fmaf(tr[mt][r], w0v, acc[mt][nt][r] + b1v);
          hbuf[hb + (mt * 16 + qd * 4 + r) * HST + nt * 16 + l15] = (short)f2bf(tanh_fast(v));
        }
    }

    // ---- pack group 2 (loads covered L1 epilogue latency) ----
    if (ii == 0) {
#pragma unroll
      for (int mt = 0; mt < 2; mt++)
#pragma unroll
        for (int kp = 0; kp < 2; kp++)
          XN[mt][4 + kp] = pack_bf8(sg[mt][kp][0], sg[mt][kp][1]);
    }

    // ---- Layer 2: [32,128] x [128,112] (kt=3: K rows 112..127 are B-zero) ----
    short8 HA[2][4];
#pragma unroll
    for (int mt = 0; mt < 2; mt++) {
      int ro = hb + (mt * 16 + l15) * HST;
#pragma unroll
      for (int kt = 0; kt < 3; kt++) HA[mt][kt] = ldh(ro + kt * 32 + qd * 8);
      HA[mt][3] = ldh(ro + 96 + (qd & 1) * 8);  // qd>=2 garbage x B-zero = 0
    }
#pragma unroll
    for (int nt = 0; nt < 7; nt++) {
      f32x4 zzz = {0.f, 0.f, 0.f, 0.f};
      acc[0][nt] = zzz; acc[1][nt] = zzz;
    }
#pragma unroll
    for (int kt = 0; kt < 4; kt++)
#pragma unroll
      for (int nt = 0; nt < 7; nt++) {
        short8 bf = *(const short8*)&wbuf[(42 + kt * 7 + nt) * 512 + lane * 8];
        acc[0][nt] = __builtin_amdgcn_mfma_f32_16x16x32_bf16(HA[0][kt], bf, acc[0][nt], 0, 0, 0);
        acc[1][nt] = __builtin_amdgcn_mfma_f32_16x16x32_bf16(HA[1][kt], bf, acc[1][nt], 0, 0, 0);
      }
#pragma unroll
    for (int nt = 0; nt < 7; nt++) {
      float b2v = cbl[224 + nt * 16 + l15];
#pragma unroll
      for (int mt = 0; mt < 2; mt++)
#pragma unroll
        for (int r = 0; r < 4; r++) {
          float v = acc[mt][nt][r] + b2v;
          hbuf[hb + (mt * 16 + qd * 4 + r) * HST + nt * 16 + l15] = (short)f2bf(tanh_fast(v));
        }
    }

    // ---- Layer 3 (scatter-folded): [32,128] x [128,96] -> q ----
#pragma unroll
    for (int mt = 0; mt < 2; mt++) {
      int ro = hb + (mt * 16 + l15) * HST;
#pragma unroll
      for (int kt = 0; kt < 3; kt++) HA[mt][kt] = ldh(ro + kt * 32 + qd * 8);
      HA[mt][3] = ldh(ro + 96 + (qd & 1) * 8);
    }
    f32x4 qa[2][6];
#pragma unroll
    for (int nt = 0; nt < 6; nt++) {
      f32x4 zzz = {0.f, 0.f, 0.f, 0.f};
      qa[0][nt] = zzz; qa[1][nt] = zzz;
    }
#pragma unroll
    for (int kt = 0; kt < 4; kt++)
#pragma unroll
      for (int nt = 0; nt < 6; nt++) {
        short8 bf = *(const short8*)&wbuf[(70 + kt * 6 + nt) * 512 + lane * 8];
        qa[0][nt] = __builtin_amdgcn_mfma_f32_16x16x32_bf16(HA[0][kt], bf, qa[0][nt], 0, 0, 0);
        qa[1][nt] = __builtin_amdgcn_mfma_f32_16x16x32_bf16(HA[1][kt], bf, qa[1][nt], 0, 0, 0);
      }

    // ---- QP epilogue ----
#pragma unroll
    for (int mt = 0; mt < 2; mt++) {
#pragma unroll
      for (int nt = 0; nt < 6; nt++) {
        float bq = cbl[336 + nt * 16 + l15];
        qa[mt][nt][0] += bq; qa[mt][nt][1] += bq;
        qa[mt][nt][2] += bq; qa[mt][nt][3] += bq;
      }
      f32x4 rs = {0.f, 0.f, 0.f, 0.f};
#pragma unroll
      for (int nt = 0; nt < 6; nt++) rs += qa[mt][nt] * qa[mt][nt];
      float rv[4];
#pragma unroll
      for (int r = 0; r < 4; r++) {
        float v = rs[r];
        v += __shfl_xor(v, 1);
        v += __shfl_xor(v, 2);
        v += __shfl_xor(v, 4);
        v += __shfl_xor(v, 8);
        rv[r] = v;
      }
      float r2 = rv[l15 & 3];
      float s = __builtin_amdgcn_exp2f(__builtin_amdgcn_logf(r2) * 0.333333333333f);
#pragma unroll
      for (int itn = 0; itn < 8; itn++) {
        float one = 1.f + s;
        float fv = fmaf(s * one, one, -r2);
        float fp = one * fmaf(2.f, s, one);
        s = fmaxf(s - fv * __builtin_amdgcn_rcpf(fp), 0.f);
      }
      float myinv = -__builtin_amdgcn_rcpf(1.f + s);
#pragma unroll
      for (int r = 0; r < 4; r++) {
        float inv = __shfl(myinv, (lane & 48) | r);
        float* orow = out + (size_t)(rb + mt * 16 + qd * 4 + r) * 96;
#pragma unroll
        for (int nt = 0; nt < 6; nt++)
          orow[nt * 16 + l15] = qa[mt][nt][r] * inv;
      }
    }

    // ---- rotate next-tile fragments into place ----
    if (ii == 0) {
#pragma unroll
      for (int mt = 0; mt < 2; mt++)
#pragma unroll
        for (int kt = 0; kt < 6; kt++) XA[mt][kt] = XN[mt][kt];
      tc0 = tn0; tc1 = tn1;
    }
  }
}

extern "C" void kernel_launch(void* const* d_in, const int* in_sizes, int n_in,
                              void* d_out, int out_size, void* d_ws, size_t ws_size,
                              hipStream_t stream) {
  const float* z  = (const float*)d_in[0];
  const float* t  = (const float*)d_in[1];
  const float* W1 = (const float*)d_in[2];
  const float* b1 = (const float*)d_in[3];
  const float* W2 = (const float*)d_in[4];
  const float* b2 = (const float*)d_in[5];
  const float* W3 = (const float*)d_in[6];
  const float* b3 = (const float*)d_in[7];
  float* out = (float*)d_out;
  int B = in_sizes[0] / 192;                 // 131072

  short* pw = (short*)d_ws;                  // 97,984 bytes used
  cvx_prep<<<190, 256, 0, stream>>>(W1, b1, W2, b2, W3, b3, pw);
  cvx_main<<<B / 512, 512, 0, stream>>>(z, t, pw, out);
}